// Round 3
// baseline (245.110 us; speedup 1.0000x reference)
//
#include <hip/hip_runtime.h>
#include <math.h>

#define NB 65536
#define DIM 256

// Staged-W geometry (fp16, padded-linear k-rows).
// ROWB = 264 halves = 528 B = 33*16B: ds_read_b128-aligned, start banks spread
// uniformly across lanes (8 lanes per 16B slot = structural minimum).
// Phase tile = 32 cols x 4 experts = 72 KiB (9 KiB per wave with 512 threads).
#define ROWB   528              // bytes per k-row (K=256 halves + 8 pad halves)
#define ESEC   18432            // bytes per expert section: 32*528=16896, pad to 18K
#define STAGEB 73728            // bytes per nt-stage: 4 experts * ESEC (=72 KiB)
#define NTILE  8                // phases per layer (32 cols each)
#define LAYB   589824           // bytes per layer in W16 image: 8 nt-stages

typedef _Float16 half8  __attribute__((ext_vector_type(8)));   // 4 VGPRs
typedef _Float16 half2v __attribute__((ext_vector_type(2)));
typedef float    f32x4  __attribute__((ext_vector_type(4)));

// ---- W pre-pass: fp32 [e][k][n] -> fp16 staged image [L][nt32][e][n32][k] ----
// One thread per 16B output chunk (3 layers * 4 e * 32 k-chunks * 256 n = 98304).
__global__ __launch_bounds__(256) void convert_w(
    const float* __restrict__ W1, const float* __restrict__ W2,
    const float* __restrict__ W3, char* __restrict__ W16T)
{
  const int g  = blockIdx.x * 256 + threadIdx.x;
  const int n  = g & 255;          // global output column
  const int k8 = (g >> 8) & 31;    // 16-byte k chunk (8 halves)
  const int e  = (g >> 13) & 3;
  const int L  = g >> 15;
  const float* WL  = (L == 0) ? W1 : (L == 1) ? W2 : W3;
  const float* src = WL + (size_t)e * DIM * DIM + (size_t)k8 * 8 * DIM + n;
  half8 h;
  #pragma unroll
  for (int j = 0; j < 8; ++j) h[j] = (_Float16)src[(size_t)j * DIM];
  *(half8*)(W16T + (size_t)L * LAYB + (size_t)(n >> 5) * STAGEB
            + e * ESEC + (n & 31) * ROWB + k8 * 16) = h;
}

// One cyclic-MoE layer: Out[b,:] = act( sum_e C[b,e]*(X[b,:] @ W_e + bias_e) )
// R3 restructure: m_rep = 4 (each B fragment feeds 4 MFMAs) to halve the LDS
// read pipe (R2 analysis: LDS B-reads 65k cyc/CU/layer vs MFMA 40k).
//   - block = 512 threads, 8 waves = (cs in {0,1} col-half) x (ms in {0..3}
//     row-group); each wave owns 64 rows x 16 cols of a 32-col phase tile.
//   - 8 phases; stage = all 4 experts x 32 cols (72 KB), double-buffered,
//     global_load_lds dwordx4 prefetch issued at phase start.
//   - MFMA C/D mapping hardcoded (probe-proven prior session + guide m89/m91:
//     row = (lane>>4)*4 + reg, col = lane&15): enables bias CSE and static
//     addressing. A/B fragment load patterns unchanged from verified kernel.
//   - epilogue moved AFTER the phase barrier: scattered 2B stores drain during
//     the next phase's compute instead of stalling the barrier.
template<bool WF16, bool IN_F16, bool OUT_F16, bool RELU>
__global__ __launch_bounds__(512, 2) void moe_layer(
    const void* __restrict__ Xin_,
    const float* __restrict__ phi,
    const float* __restrict__ Wf32,   // [4,256,256] fp32 (fallback path only)
    const char* __restrict__ W16,     // this layer's staged fp16 image (LAYB bytes)
    const float* __restrict__ bias,   // [4,256] fp32
    void* __restrict__ Out_,
    float acc_scale, float store_scale)
{
  __shared__ __attribute__((aligned(16))) char sStage[2][STAGEB];  // 2 x 72 KB
  __shared__ float sC[256][4];       // per-row expert coefficients
  __shared__ float sBias[4][DIM];

  const int tid  = threadIdx.x;
  const int row0 = blockIdx.x * 256;
  const int wave = tid >> 6;
  const int lane = tid & 63;
  const int quad = lane >> 4;
  const int l15  = lane & 15;
  const int ms   = wave & 3;         // row group: 64 rows
  const int cs   = wave >> 2;        // col half: 16 cols

  // --- staging helper ---
  auto stage = [&](int buf, int nt_) {
    if constexpr (WF16) {
      // Pure async copy: wave w owns 9 KiB of the 72 KB tile (linear).
      const char* g_ = W16 + (size_t)nt_ * STAGEB + wave * 9216 + lane * 16;
      char*       l_ = &sStage[buf][wave * 9216];
      #pragma unroll
      for (int j = 0; j < 9; ++j)
        __builtin_amdgcn_global_load_lds(
            (const __attribute__((address_space(1))) unsigned int*)(g_ + j * 1024),
            (__attribute__((address_space(3))) unsigned int*)(l_ + j * 1024),
            16, 0, 0);
    } else {
      // fp32 fallback: read W[e][k][n] float4 pairs, cvt, half2 LDS writes.
      char* sb = &sStage[buf][0];
      #pragma unroll
      for (int it = 0; it < 8; ++it) {
        const int p  = it * 512 + tid;   // 4096 (e, k-pair, n4) units
        const int e  = p >> 10;
        const int k2 = (p & 1023) >> 3;  // 0..127
        const int ng = p & 7;            // n-group of 4 cols
        const float* Wp = Wf32 + (size_t)e * DIM * DIM
                        + (size_t)(k2 * 2) * DIM + nt_ * 32 + ng * 4;
        const float4 v0 = *(const float4*)Wp;
        const float4 v1 = *(const float4*)(Wp + DIM);
        const float s0[4] = {v0.x, v0.y, v0.z, v0.w};
        const float s1[4] = {v1.x, v1.y, v1.z, v1.w};
        #pragma unroll
        for (int j = 0; j < 4; ++j) {
          half2v h;
          h[0] = (_Float16)s0[j];
          h[1] = (_Float16)s1[j];
          *(half2v*)(sb + e * ESEC + (ng * 4 + j) * ROWB + k2 * 4) = h;
        }
      }
    }
  };

  // --- prologue: kick off first stage, coefficients, bias, A-fragments ---
  stage(0, 0);

  if (tid < 256) {
    const float w  = phi[row0 + tid] * (float)(2.0 / M_PI);  // [0,4]
    const int   wi = (int)w;                                 // trunc toward zero
    const float w2 = w * w, w3 = w2 * w;
    const float cf[4] = {
      -0.5f * w + w2 - 0.5f * w3,
      -2.5f * w2 + 1.5f * w3,
       0.5f * w + 2.0f * w2 - 1.5f * w3,
      -0.5f * w2 + 0.5f * w3 };
    #pragma unroll
    for (int e = 0; e < 4; ++e) sC[tid][e] = cf[(e + 1 - wi) & 3];
  }
  #pragma unroll
  for (int i = tid; i < 4 * DIM; i += 512) sBias[i >> 8][i & 255] = bias[i];

  // A fragments (fp16): wave owns 64 rows = 4 m-tiles x 8 k-chunks (128 VGPR).
  half8 afr[4][8];
  #pragma unroll
  for (int m = 0; m < 4; ++m) {
    const size_t row = (size_t)(row0 + ms * 64 + m * 16 + l15);
    if constexpr (IN_F16) {
      const _Float16* xr = (const _Float16*)Xin_ + row * DIM;
      #pragma unroll
      for (int kb = 0; kb < 8; ++kb)
        afr[m][kb] = *(const half8*)(xr + kb * 32 + quad * 8);
    } else {
      const float* xr = (const float*)Xin_ + row * DIM;
      #pragma unroll
      for (int kb = 0; kb < 8; ++kb) {
        const float4 a = *(const float4*)(xr + kb * 32 + quad * 8);
        const float4 b = *(const float4*)(xr + kb * 32 + quad * 8 + 4);
        half8 h;
        h[0] = (_Float16)a.x; h[1] = (_Float16)a.y;
        h[2] = (_Float16)a.z; h[3] = (_Float16)a.w;
        h[4] = (_Float16)b.x; h[5] = (_Float16)b.y;
        h[6] = (_Float16)b.z; h[7] = (_Float16)b.w;
        afr[m][kb] = h;
      }
    }
  }

  __syncthreads();   // stage(0) + sC + sBias ready

  // Per-row mixing coefficients in registers (hardcoded C/D row mapping).
  float creg[4][4][4];
  #pragma unroll
  for (int m = 0; m < 4; ++m)
    #pragma unroll
    for (int r = 0; r < 4; ++r) {
      const int rl = ms * 64 + m * 16 + quad * 4 + r;
      #pragma unroll
      for (int e = 0; e < 4; ++e) creg[m][r][e] = sC[rl][e];
    }

  // --- main loop: 8 n-tile phases, double-buffered ---
  int cur = 0;
  for (int nt = 0; nt < NTILE; ++nt) {
    if (nt < NTILE - 1) stage(cur ^ 1, nt + 1);  // prefetch next tile

    const char* sb = &sStage[cur][0];
    float fin[4][4];
    #pragma unroll
    for (int m = 0; m < 4; ++m)
      #pragma unroll
      for (int r = 0; r < 4; ++r) fin[m][r] = 0.f;

    #pragma unroll
    for (int e = 0; e < 4; ++e) {
      f32x4 acc[4];
      #pragma unroll
      for (int m = 0; m < 4; ++m) acc[m] = (f32x4){0.f, 0.f, 0.f, 0.f};

      #pragma unroll
      for (int kb = 0; kb < 8; ++kb) {
        const half8 b = *(const half8*)(sb + e * ESEC + (cs * 16 + l15) * ROWB
                                        + kb * 64 + quad * 16);
        acc[0] = __builtin_amdgcn_mfma_f32_16x16x32_f16(afr[0][kb], b, acc[0], 0, 0, 0);
        acc[1] = __builtin_amdgcn_mfma_f32_16x16x32_f16(afr[1][kb], b, acc[1], 0, 0, 0);
        acc[2] = __builtin_amdgcn_mfma_f32_16x16x32_f16(afr[2][kb], b, acc[2], 0, 0, 0);
        acc[3] = __builtin_amdgcn_mfma_f32_16x16x32_f16(afr[3][kb], b, acc[3], 0, 0, 0);
      }

      #pragma unroll
      for (int m = 0; m < 4; ++m)
        #pragma unroll
        for (int r = 0; r < 4; ++r)
          fin[m][r] += creg[m][r][e] * acc[m][r];
    }

    __syncthreads();   // stage reads done; prefetched buffer landed (vmcnt drain)

    // --- epilogue (post-barrier: stores retire during next phase's compute) ---
    const int n_l = nt * 32 + cs * 16 + l15;   // col = lane&15 (hardcoded C/D map)
    float be[4];
    #pragma unroll
    for (int e = 0; e < 4; ++e) be[e] = sBias[e][n_l];
    #pragma unroll
    for (int m = 0; m < 4; ++m)
      #pragma unroll
      for (int r = 0; r < 4; ++r) {
        const int row_l = ms * 64 + m * 16 + quad * 4 + r;   // row = quad*4+reg
        float v = acc_scale * fin[m][r];
        #pragma unroll
        for (int e = 0; e < 4; ++e) v += creg[m][r][e] * be[e];
        if (RELU) v = fmaxf(v, 0.f);
        v *= store_scale;
        const size_t idx = (size_t)(row0 + row_l) * DIM + n_l;
        if (OUT_F16) ((_Float16*)Out_)[idx] = (_Float16)v;
        else         ((float*)Out_)[idx] = v;
      }

    cur ^= 1;
  }
}

extern "C" void kernel_launch(void* const* d_in, const int* in_sizes, int n_in,
                              void* d_out, int out_size, void* d_ws, size_t ws_size,
                              hipStream_t stream) {
  const float* X   = (const float*)d_in[0];
  const float* phi = (const float*)d_in[1];
  const float* W1  = (const float*)d_in[2];
  const float* b1  = (const float*)d_in[3];
  const float* W2  = (const float*)d_in[4];
  const float* b2  = (const float*)d_in[5];
  const float* W3  = (const float*)d_in[6];
  const float* b3  = (const float*)d_in[7];

  // Buffer plan (proven):
  //   H1 fp16 (32 MB) -> lower half of d_out.
  //   H2 fp16 (32 MB) -> d_ws if it fits, else dead X buffer (restored by harness).
  //   W16 image (~1.7 MB) -> d_ws tail when room; else fp32 staging path.
  //   H2 stored pre-scaled by 1/8; layer 3 undoes (x8).
  const size_t h2_bytes  = (size_t)NB * DIM * sizeof(_Float16);
  const size_t w16_bytes = (size_t)3 * LAYB;

  _Float16* H1  = (_Float16*)d_out;
  _Float16* H2;
  char*     W16 = nullptr;
  if (ws_size >= h2_bytes + w16_bytes) {
    H2  = (_Float16*)d_ws;
    W16 = (char*)d_ws + h2_bytes;
  } else if (ws_size >= h2_bytes) {
    H2 = (_Float16*)d_ws;                 // no W16 room -> fp32 staging
  } else if (ws_size >= w16_bytes) {
    W16 = (char*)d_ws;
    H2  = (_Float16*)d_in[0];
  } else {
    H2 = (_Float16*)d_in[0];
  }
  float* out = (float*)d_out;

  dim3 grid(NB / 256);
  dim3 block(512);

  if (W16) {
    convert_w<<<dim3(384), dim3(256), 0, stream>>>(W1, W2, W3, W16);
    moe_layer<true, false, true,  true ><<<grid, block, 0, stream>>>(X,  phi, nullptr, W16,            b1, H1,  1.0f, 1.0f);
    moe_layer<true, true,  true,  true ><<<grid, block, 0, stream>>>(H1, phi, nullptr, W16 + LAYB,     b2, H2,  1.0f, 0.125f);
    moe_layer<true, true,  false, false><<<grid, block, 0, stream>>>(H2, phi, nullptr, W16 + 2 * LAYB, b3, out, 8.0f, 1.0f);
  } else {
    moe_layer<false, false, true,  true ><<<grid, block, 0, stream>>>(X,  phi, W1, nullptr, b1, H1,  1.0f, 1.0f);
    moe_layer<false, true,  true,  true ><<<grid, block, 0, stream>>>(H1, phi, W2, nullptr, b2, H2,  1.0f, 0.125f);
    moe_layer<false, true,  false, false><<<grid, block, 0, stream>>>(H2, phi, W3, nullptr, b3, out, 8.0f, 1.0f);
  }
}